// Round 4
// baseline (753.478 us; speedup 1.0000x reference)
//
#include <hip/hip_runtime.h>

// ---------------------------------------------------------------------------
// GCN 3-layer forward on MI355X.
// Pipeline: build deg -> dinv -> CSR(by dst, packed {src,w}) once; per layer:
//   T = H @ W  (fp32 tiled GEMM, W in LDS)
//   H' = relu( segsum_{dst}( T[src] * w_e ) + b )
// R1: GEMM 1024-thr blocks, 128 rows/block, 2 blocks/CU (128KB LDS).
// R2: prop float4 row gathers, packed int2 edge records, fp64 accumulators.
// R3: prop de-shfl'd — one 32-lane (F=128) / 16-lane (F=64) group per node,
//     group-uniform epk loads, 4x unrolled independent gathers (8 rows in
//     flight per wave). No LDS, no bpermute, no cross-group reduce.
// ---------------------------------------------------------------------------

__global__ void k_init_deg(int* __restrict__ deg, int n) {
    int i = blockIdx.x * blockDim.x + threadIdx.x;
    if (i < n) deg[i] = 1;  // self-loop contributes 1
}

__global__ void k_hist(const int* __restrict__ dst, int* __restrict__ deg, int E) {
    int e = blockIdx.x * blockDim.x + threadIdx.x;
    if (e < E) atomicAdd(&deg[dst[e]], 1);
}

// per-block (1024 elems) local exclusive scan; block totals to bsum
__global__ __launch_bounds__(256) void k_scan1(const int* __restrict__ deg,
                                               int* __restrict__ loc,
                                               int* __restrict__ bsum, int n) {
    __shared__ int sh[256];
    int tid = threadIdx.x;
    int base = blockIdx.x * 1024 + tid * 4;
    int v[4];
#pragma unroll
    for (int j = 0; j < 4; j++) v[j] = (base + j < n) ? deg[base + j] : 0;
    int tsum = v[0] + v[1] + v[2] + v[3];
    int val = tsum;
    sh[tid] = val;
    __syncthreads();
    for (int off = 1; off < 256; off <<= 1) {
        int o = (tid >= off) ? sh[tid - off] : 0;
        __syncthreads();
        val += o;
        sh[tid] = val;
        __syncthreads();
    }
    if (tid == 255) bsum[blockIdx.x] = val;
    int run = val - tsum;  // exclusive over thread sums
#pragma unroll
    for (int j = 0; j < 4; j++) {
        if (base + j < n) loc[base + j] = run;
        run += v[j];
    }
}

// single block: exclusive scan of nb block sums (nb <= 256)
__global__ __launch_bounds__(256) void k_scan2(int* __restrict__ bsum, int nb) {
    __shared__ int sh[256];
    int tid = threadIdx.x;
    int orig = (tid < nb) ? bsum[tid] : 0;
    int val = orig;
    sh[tid] = val;
    __syncthreads();
    for (int off = 1; off < 256; off <<= 1) {
        int o = (tid >= off) ? sh[tid - off] : 0;
        __syncthreads();
        val += o;
        sh[tid] = val;
        __syncthreads();
    }
    if (tid < nb) bsum[tid] = val - orig;      // exclusive
    if (tid == nb - 1) bsum[nb] = val;         // total = E + N
}

__global__ void k_scan3(const int* __restrict__ deg, int* __restrict__ offs,
                        const int* __restrict__ bsum, int* __restrict__ cursor,
                        float* __restrict__ dinv, int n, int nb) {
    int i = blockIdx.x * blockDim.x + threadIdx.x;
    if (i < n) {
        int off = offs[i] + bsum[i >> 10];
        offs[i] = off;
        cursor[i] = off;
        dinv[i] = rsqrtf((float)deg[i]);
    }
    if (i == 0) offs[n] = bsum[nb];
}

__global__ void k_fill(const int* __restrict__ esrc, const int* __restrict__ edst,
                       const float* __restrict__ dinv, int* __restrict__ cursor,
                       int2* __restrict__ epk, int E, int n) {
    int e = blockIdx.x * blockDim.x + threadIdx.x;
    if (e < E) {
        int s = esrc[e], d = edst[e];
        int pos = atomicAdd(&cursor[d], 1);
        float w = dinv[s] * dinv[d];
        epk[pos] = int2{s, __float_as_int(w)};
    } else if (e < E + n) {
        int i = e - E;
        int pos = atomicAdd(&cursor[i], 1);
        float di = dinv[i];
        epk[pos] = int2{i, __float_as_int(di * di)};
    }
}

// T[N,F] = H[N,128] @ W[128,F]. W staged in LDS (F*512 B), 128 rows/block,
// 1024 threads, each thread: RPT rows x 1 float4 col. 2 blocks/CU target.
template <int F>
__global__ __launch_bounds__(1024, 8) void k_gemm(const float* __restrict__ H,
                                                  const float* __restrict__ W,
                                                  float* __restrict__ T, int n) {
    constexpr int TX = F / 4;          // 32 (F=128) or 16 (F=64)
    constexpr int TY = 1024 / TX;      // 32 or 64
    constexpr int RPT = 128 / TY;      // 4 or 2
    __shared__ float Wl[128 * F];
    int tid = threadIdx.x;
#pragma unroll
    for (int i = 0; i < (128 * F) / 4096; i++)
        *(float4*)&Wl[tid * 4 + i * 4096] = *(const float4*)&W[tid * 4 + i * 4096];
    __syncthreads();
    int tx = tid % TX, ty = tid / TX;
    int row0 = blockIdx.x * 128 + ty * RPT;
    // clamp OOB rows (values unused; stores are guarded) -> unconditional loads
    const float* hp[RPT];
#pragma unroll
    for (int i = 0; i < RPT; i++) hp[i] = H + (size_t)min(row0 + i, n - 1) * 128;
    float4 acc[RPT];
#pragma unroll
    for (int i = 0; i < RPT; i++) acc[i] = float4{0.f, 0.f, 0.f, 0.f};
#pragma unroll 2
    for (int k4 = 0; k4 < 32; k4++) {
        float4 xq[RPT];
#pragma unroll
        for (int i = 0; i < RPT; i++) xq[i] = *(const float4*)(hp[i] + k4 * 4);
#pragma unroll
        for (int kk = 0; kk < 4; kk++) {
            float4 wv = *(const float4*)&Wl[(k4 * 4 + kk) * F + tx * 4];
#pragma unroll
            for (int i = 0; i < RPT; i++) {
                float xs = (&xq[i].x)[kk];
                acc[i].x += xs * wv.x;
                acc[i].y += xs * wv.y;
                acc[i].z += xs * wv.z;
                acc[i].w += xs * wv.w;
            }
        }
    }
#pragma unroll
    for (int i = 0; i < RPT; i++) {
        int r = row0 + i;
        if (r < n) *(float4*)&T[(size_t)r * F + tx * 4] = acc[i];
    }
}

// R3 prop: one GRP-lane group per dst node (GRP = F/4 -> full row as float4).
// Edge records read directly (group-uniform address, L1 broadcast, line reuse
// across j). 4x unrolled -> 4 independent row gathers in flight per group.
// f64 accumulators: result independent of CSR fill order (atomic, nondet).
template <int F, bool RELU>
__global__ __launch_bounds__(256) void k_prop(const float* __restrict__ T,
                                              const int* __restrict__ offs,
                                              const int2* __restrict__ epk,
                                              const float* __restrict__ bias,
                                              float* __restrict__ Out, int n) {
    constexpr int GRP = F / 4;              // 32 (F=128) or 16 (F=64)
    int g  = (int)((blockIdx.x * blockDim.x + threadIdx.x) / GRP);  // node id
    int fl = threadIdx.x % GRP;             // feature lane
    if (g >= n) return;
    int j = offs[g], end = offs[g + 1];
    double a0 = 0.0, a1 = 0.0, a2 = 0.0, a3 = 0.0;
    for (; j + 4 <= end; j += 4) {
        int2 e0 = epk[j + 0];
        int2 e1 = epk[j + 1];
        int2 e2 = epk[j + 2];
        int2 e3 = epk[j + 3];
        float4 v0 = *(const float4*)&T[(size_t)e0.x * F + fl * 4];
        float4 v1 = *(const float4*)&T[(size_t)e1.x * F + fl * 4];
        float4 v2 = *(const float4*)&T[(size_t)e2.x * F + fl * 4];
        float4 v3 = *(const float4*)&T[(size_t)e3.x * F + fl * 4];
        float w0 = __int_as_float(e0.y), w1 = __int_as_float(e1.y);
        float w2 = __int_as_float(e2.y), w3 = __int_as_float(e3.y);
        a0 += (double)(w0 * v0.x) + (double)(w1 * v1.x) +
              (double)(w2 * v2.x) + (double)(w3 * v3.x);
        a1 += (double)(w0 * v0.y) + (double)(w1 * v1.y) +
              (double)(w2 * v2.y) + (double)(w3 * v3.y);
        a2 += (double)(w0 * v0.z) + (double)(w1 * v1.z) +
              (double)(w2 * v2.z) + (double)(w3 * v3.z);
        a3 += (double)(w0 * v0.w) + (double)(w1 * v1.w) +
              (double)(w2 * v2.w) + (double)(w3 * v3.w);
    }
    for (; j < end; j++) {
        int2 e = epk[j];
        float w = __int_as_float(e.y);
        float4 v = *(const float4*)&T[(size_t)e.x * F + fl * 4];
        a0 += (double)(w * v.x);
        a1 += (double)(w * v.y);
        a2 += (double)(w * v.z);
        a3 += (double)(w * v.w);
    }
    float4 b = *(const float4*)&bias[fl * 4];
    float r0 = (float)a0 + b.x;
    float r1 = (float)a1 + b.y;
    float r2 = (float)a2 + b.z;
    float r3 = (float)a3 + b.w;
    if (RELU) {
        r0 = fmaxf(r0, 0.f); r1 = fmaxf(r1, 0.f);
        r2 = fmaxf(r2, 0.f); r3 = fmaxf(r3, 0.f);
    }
    *(float4*)&Out[(size_t)g * F + fl * 4] = float4{r0, r1, r2, r3};
}

extern "C" void kernel_launch(void* const* d_in, const int* in_sizes, int n_in,
                              void* d_out, int out_size, void* d_ws, size_t ws_size,
                              hipStream_t stream) {
    const float* x  = (const float*)d_in[0];
    const int*   ei = (const int*)d_in[1];
    const float* W1 = (const float*)d_in[2];
    const float* b1 = (const float*)d_in[3];
    const float* W2 = (const float*)d_in[4];
    const float* b2 = (const float*)d_in[5];
    const float* W3 = (const float*)d_in[6];
    const float* b3 = (const float*)d_in[7];
    float* out = (float*)d_out;

    const int HID = in_sizes[3];            // 128
    const int IN  = in_sizes[2] / HID;      // 128
    const int N   = in_sizes[0] / IN;       // 100000
    const int E   = in_sizes[1] / 2;        // 1600000
    const int nb  = (N + 1023) / 1024;      // scan blocks

    const int* esrc = ei;
    const int* edst = ei + E;

    // workspace carve-up (256B aligned)
    char* p = (char*)d_ws;
    auto alloc = [&](size_t bytes) {
        void* r = (void*)p;
        p += (bytes + 255) & ~(size_t)255;
        return r;
    };
    int*   deg    = (int*)alloc((size_t)N * 4);
    float* dinv   = (float*)alloc((size_t)N * 4);
    int*   offs   = (int*)alloc((size_t)(N + 1) * 4);
    int*   bsum   = (int*)alloc((size_t)(nb + 2) * 4);
    int*   cursor = (int*)alloc((size_t)N * 4);
    int2*  epk    = (int2*)alloc((size_t)(E + N) * 8);
    float* t0     = (float*)alloc((size_t)N * 128 * 4);
    float* h0     = (float*)alloc((size_t)N * 128 * 4);
    (void)ws_size; (void)n_in; (void)out_size;

    const int B = 256;
    // --- graph norm + CSR build (once; reused by all 3 layers) ---
    k_init_deg<<<(N + B - 1) / B, B, 0, stream>>>(deg, N);
    k_hist<<<(E + B - 1) / B, B, 0, stream>>>(edst, deg, E);
    k_scan1<<<nb, B, 0, stream>>>(deg, offs, bsum, N);
    k_scan2<<<1, B, 0, stream>>>(bsum, nb);
    k_scan3<<<(N + B - 1) / B, B, 0, stream>>>(deg, offs, bsum, cursor, dinv, N, nb);
    k_fill<<<(E + N + B - 1) / B, B, 0, stream>>>(esrc, edst, dinv, cursor, epk, E, N);

    const int gb    = (N + 127) / 128;                     // gemm row-blocks
    const int pb128 = (int)(((size_t)N * 32 + B - 1) / B); // prop F=128 blocks
    const int pb64  = (int)(((size_t)N * 16 + B - 1) / B); // prop F=64 blocks
    // --- layer 1 ---
    k_gemm<128><<<gb, 1024, 0, stream>>>(x, W1, t0, N);
    k_prop<128, true><<<pb128, B, 0, stream>>>(t0, offs, epk, b1, h0, N);
    // --- layer 2 ---
    k_gemm<128><<<gb, 1024, 0, stream>>>(h0, W2, t0, N);
    k_prop<128, true><<<pb128, B, 0, stream>>>(t0, offs, epk, b2, h0, N);
    // --- layer 3 (OUT=64, no relu, into d_out) ---
    k_gemm<64><<<gb, 1024, 0, stream>>>(h0, W3, t0, N);
    k_prop<64, false><<<pb64, B, 0, stream>>>(t0, offs, epk, b3, out, N);
}

// Round 5
// 589.172 us; speedup vs baseline: 1.2789x; 1.2789x over previous
//
#include <hip/hip_runtime.h>
#include <hip/hip_fp16.h>

// ---------------------------------------------------------------------------
// GCN 3-layer forward on MI355X.
// Pipeline: build deg -> dinv -> CSR(by dst, packed {src,w}) once; per layer:
//   T = H @ W  (fp32 tiled GEMM, W in LDS) stored as FP16
//   H' = relu( segsum_{dst}( T[src] * w_e ) + b )   (gather fp16, acc fp64)
// R1: GEMM 1024-thr blocks, 128 rows/block, 2 blocks/CU (128KB LDS).
// R2: prop float4 row gathers, packed int2 edge records, fp64 accumulators.
// R3: prop de-shfl'd — one F/4-lane group per node, direct epk loads.
// R4: T stored fp16 — halves random-gather bytes (the measured fabric ceiling
//     ~3.3 TB/s L2-miss BW was the bottleneck; 3 structures all ~120 µs).
// ---------------------------------------------------------------------------

struct h4 { __half2 a, b; };  // 4 halves = 8 B

__global__ void k_init_deg(int* __restrict__ deg, int n) {
    int i = blockIdx.x * blockDim.x + threadIdx.x;
    if (i < n) deg[i] = 1;  // self-loop contributes 1
}

__global__ void k_hist(const int* __restrict__ dst, int* __restrict__ deg, int E) {
    int e = blockIdx.x * blockDim.x + threadIdx.x;
    if (e < E) atomicAdd(&deg[dst[e]], 1);
}

// per-block (1024 elems) local exclusive scan; block totals to bsum
__global__ __launch_bounds__(256) void k_scan1(const int* __restrict__ deg,
                                               int* __restrict__ loc,
                                               int* __restrict__ bsum, int n) {
    __shared__ int sh[256];
    int tid = threadIdx.x;
    int base = blockIdx.x * 1024 + tid * 4;
    int v[4];
#pragma unroll
    for (int j = 0; j < 4; j++) v[j] = (base + j < n) ? deg[base + j] : 0;
    int tsum = v[0] + v[1] + v[2] + v[3];
    int val = tsum;
    sh[tid] = val;
    __syncthreads();
    for (int off = 1; off < 256; off <<= 1) {
        int o = (tid >= off) ? sh[tid - off] : 0;
        __syncthreads();
        val += o;
        sh[tid] = val;
        __syncthreads();
    }
    if (tid == 255) bsum[blockIdx.x] = val;
    int run = val - tsum;  // exclusive over thread sums
#pragma unroll
    for (int j = 0; j < 4; j++) {
        if (base + j < n) loc[base + j] = run;
        run += v[j];
    }
}

// single block: exclusive scan of nb block sums (nb <= 256)
__global__ __launch_bounds__(256) void k_scan2(int* __restrict__ bsum, int nb) {
    __shared__ int sh[256];
    int tid = threadIdx.x;
    int orig = (tid < nb) ? bsum[tid] : 0;
    int val = orig;
    sh[tid] = val;
    __syncthreads();
    for (int off = 1; off < 256; off <<= 1) {
        int o = (tid >= off) ? sh[tid - off] : 0;
        __syncthreads();
        val += o;
        sh[tid] = val;
        __syncthreads();
    }
    if (tid < nb) bsum[tid] = val - orig;      // exclusive
    if (tid == nb - 1) bsum[nb] = val;         // total = E + N
}

__global__ void k_scan3(const int* __restrict__ deg, int* __restrict__ offs,
                        const int* __restrict__ bsum, int* __restrict__ cursor,
                        float* __restrict__ dinv, int n, int nb) {
    int i = blockIdx.x * blockDim.x + threadIdx.x;
    if (i < n) {
        int off = offs[i] + bsum[i >> 10];
        offs[i] = off;
        cursor[i] = off;
        dinv[i] = rsqrtf((float)deg[i]);
    }
    if (i == 0) offs[n] = bsum[nb];
}

__global__ void k_fill(const int* __restrict__ esrc, const int* __restrict__ edst,
                       const float* __restrict__ dinv, int* __restrict__ cursor,
                       int2* __restrict__ epk, int E, int n) {
    int e = blockIdx.x * blockDim.x + threadIdx.x;
    if (e < E) {
        int s = esrc[e], d = edst[e];
        int pos = atomicAdd(&cursor[d], 1);
        float w = dinv[s] * dinv[d];
        epk[pos] = int2{s, __float_as_int(w)};
    } else if (e < E + n) {
        int i = e - E;
        int pos = atomicAdd(&cursor[i], 1);
        float di = dinv[i];
        epk[pos] = int2{i, __float_as_int(di * di)};
    }
}

// T[N,F] = H[N,128] @ W[128,F], stored FP16. W staged in LDS (F*512 B),
// 128 rows/block, 1024 threads, each thread RPT rows x 1 float4 col.
template <int F>
__global__ __launch_bounds__(1024, 8) void k_gemm(const float* __restrict__ H,
                                                  const float* __restrict__ W,
                                                  __half* __restrict__ T, int n) {
    constexpr int TX = F / 4;          // 32 (F=128) or 16 (F=64)
    constexpr int TY = 1024 / TX;      // 32 or 64
    constexpr int RPT = 128 / TY;      // 4 or 2
    __shared__ float Wl[128 * F];
    int tid = threadIdx.x;
#pragma unroll
    for (int i = 0; i < (128 * F) / 4096; i++)
        *(float4*)&Wl[tid * 4 + i * 4096] = *(const float4*)&W[tid * 4 + i * 4096];
    __syncthreads();
    int tx = tid % TX, ty = tid / TX;
    int row0 = blockIdx.x * 128 + ty * RPT;
    // clamp OOB rows (values unused; stores are guarded) -> unconditional loads
    const float* hp[RPT];
#pragma unroll
    for (int i = 0; i < RPT; i++) hp[i] = H + (size_t)min(row0 + i, n - 1) * 128;
    float4 acc[RPT];
#pragma unroll
    for (int i = 0; i < RPT; i++) acc[i] = float4{0.f, 0.f, 0.f, 0.f};
#pragma unroll 2
    for (int k4 = 0; k4 < 32; k4++) {
        float4 xq[RPT];
#pragma unroll
        for (int i = 0; i < RPT; i++) xq[i] = *(const float4*)(hp[i] + k4 * 4);
#pragma unroll
        for (int kk = 0; kk < 4; kk++) {
            float4 wv = *(const float4*)&Wl[(k4 * 4 + kk) * F + tx * 4];
#pragma unroll
            for (int i = 0; i < RPT; i++) {
                float xs = (&xq[i].x)[kk];
                acc[i].x += xs * wv.x;
                acc[i].y += xs * wv.y;
                acc[i].z += xs * wv.z;
                acc[i].w += xs * wv.w;
            }
        }
    }
#pragma unroll
    for (int i = 0; i < RPT; i++) {
        int r = row0 + i;
        if (r < n) {
            h4 pk;
            pk.a = __floats2half2_rn(acc[i].x, acc[i].y);
            pk.b = __floats2half2_rn(acc[i].z, acc[i].w);
            *(h4*)&T[(size_t)r * F + tx * 4] = pk;  // 8 B store
        }
    }
}

// prop: one GRP-lane group per dst node (GRP = F/4). Each lane gathers 4
// halves (8 B) of the fp16 T row; 4 edges unrolled (4 gathers in flight).
// epk loads are group-uniform (L1 broadcast). f64 accumulators.
template <int F, bool RELU>
__global__ __launch_bounds__(256) void k_prop(const __half* __restrict__ T,
                                              const int* __restrict__ offs,
                                              const int2* __restrict__ epk,
                                              const float* __restrict__ bias,
                                              float* __restrict__ Out, int n) {
    constexpr int GRP = F / 4;              // 32 (F=128) or 16 (F=64)
    int g  = (int)((blockIdx.x * blockDim.x + threadIdx.x) / GRP);  // node id
    int fl = threadIdx.x % GRP;             // feature lane
    if (g >= n) return;
    int j = offs[g], end = offs[g + 1];
    double a0 = 0.0, a1 = 0.0, a2 = 0.0, a3 = 0.0;
    for (; j + 4 <= end; j += 4) {
        int2 e0 = epk[j + 0];
        int2 e1 = epk[j + 1];
        int2 e2 = epk[j + 2];
        int2 e3 = epk[j + 3];
        h4 v0 = *(const h4*)&T[(size_t)e0.x * F + fl * 4];
        h4 v1 = *(const h4*)&T[(size_t)e1.x * F + fl * 4];
        h4 v2 = *(const h4*)&T[(size_t)e2.x * F + fl * 4];
        h4 v3 = *(const h4*)&T[(size_t)e3.x * F + fl * 4];
        float w0 = __int_as_float(e0.y), w1 = __int_as_float(e1.y);
        float w2 = __int_as_float(e2.y), w3 = __int_as_float(e3.y);
        float2 f0a = __half22float2(v0.a), f0b = __half22float2(v0.b);
        float2 f1a = __half22float2(v1.a), f1b = __half22float2(v1.b);
        float2 f2a = __half22float2(v2.a), f2b = __half22float2(v2.b);
        float2 f3a = __half22float2(v3.a), f3b = __half22float2(v3.b);
        a0 += (double)(w0 * f0a.x) + (double)(w1 * f1a.x) +
              (double)(w2 * f2a.x) + (double)(w3 * f3a.x);
        a1 += (double)(w0 * f0a.y) + (double)(w1 * f1a.y) +
              (double)(w2 * f2a.y) + (double)(w3 * f3a.y);
        a2 += (double)(w0 * f0b.x) + (double)(w1 * f1b.x) +
              (double)(w2 * f2b.x) + (double)(w3 * f3b.x);
        a3 += (double)(w0 * f0b.y) + (double)(w1 * f1b.y) +
              (double)(w2 * f2b.y) + (double)(w3 * f3b.y);
    }
    for (; j < end; j++) {
        int2 e = epk[j];
        float w = __int_as_float(e.y);
        h4 v = *(const h4*)&T[(size_t)e.x * F + fl * 4];
        float2 fa = __half22float2(v.a), fb = __half22float2(v.b);
        a0 += (double)(w * fa.x);
        a1 += (double)(w * fa.y);
        a2 += (double)(w * fb.x);
        a3 += (double)(w * fb.y);
    }
    float4 b = *(const float4*)&bias[fl * 4];
    float r0 = (float)a0 + b.x;
    float r1 = (float)a1 + b.y;
    float r2 = (float)a2 + b.z;
    float r3 = (float)a3 + b.w;
    if (RELU) {
        r0 = fmaxf(r0, 0.f); r1 = fmaxf(r1, 0.f);
        r2 = fmaxf(r2, 0.f); r3 = fmaxf(r3, 0.f);
    }
    *(float4*)&Out[(size_t)g * F + fl * 4] = float4{r0, r1, r2, r3};
}

extern "C" void kernel_launch(void* const* d_in, const int* in_sizes, int n_in,
                              void* d_out, int out_size, void* d_ws, size_t ws_size,
                              hipStream_t stream) {
    const float* x  = (const float*)d_in[0];
    const int*   ei = (const int*)d_in[1];
    const float* W1 = (const float*)d_in[2];
    const float* b1 = (const float*)d_in[3];
    const float* W2 = (const float*)d_in[4];
    const float* b2 = (const float*)d_in[5];
    const float* W3 = (const float*)d_in[6];
    const float* b3 = (const float*)d_in[7];
    float* out = (float*)d_out;

    const int HID = in_sizes[3];            // 128
    const int IN  = in_sizes[2] / HID;      // 128
    const int N   = in_sizes[0] / IN;       // 100000
    const int E   = in_sizes[1] / 2;        // 1600000
    const int nb  = (N + 1023) / 1024;      // scan blocks

    const int* esrc = ei;
    const int* edst = ei + E;

    // workspace carve-up (256B aligned)
    char* p = (char*)d_ws;
    auto alloc = [&](size_t bytes) {
        void* r = (void*)p;
        p += (bytes + 255) & ~(size_t)255;
        return r;
    };
    int*    deg    = (int*)alloc((size_t)N * 4);
    float*  dinv   = (float*)alloc((size_t)N * 4);
    int*    offs   = (int*)alloc((size_t)(N + 1) * 4);
    int*    bsum   = (int*)alloc((size_t)(nb + 2) * 4);
    int*    cursor = (int*)alloc((size_t)N * 4);
    int2*   epk    = (int2*)alloc((size_t)(E + N) * 8);
    __half* t0     = (__half*)alloc((size_t)N * 128 * 2);
    float*  h0     = (float*)alloc((size_t)N * 128 * 4);
    (void)ws_size; (void)n_in; (void)out_size;

    const int B = 256;
    // --- graph norm + CSR build (once; reused by all 3 layers) ---
    k_init_deg<<<(N + B - 1) / B, B, 0, stream>>>(deg, N);
    k_hist<<<(E + B - 1) / B, B, 0, stream>>>(edst, deg, E);
    k_scan1<<<nb, B, 0, stream>>>(deg, offs, bsum, N);
    k_scan2<<<1, B, 0, stream>>>(bsum, nb);
    k_scan3<<<(N + B - 1) / B, B, 0, stream>>>(deg, offs, bsum, cursor, dinv, N, nb);
    k_fill<<<(E + N + B - 1) / B, B, 0, stream>>>(esrc, edst, dinv, cursor, epk, E, N);

    const int gb    = (N + 127) / 128;                     // gemm row-blocks
    const int pb128 = (int)(((size_t)N * 32 + B - 1) / B); // prop F=128 blocks
    const int pb64  = (int)(((size_t)N * 16 + B - 1) / B); // prop F=64 blocks
    // --- layer 1 ---
    k_gemm<128><<<gb, 1024, 0, stream>>>(x, W1, t0, N);
    k_prop<128, true><<<pb128, B, 0, stream>>>(t0, offs, epk, b1, h0, N);
    // --- layer 2 ---
    k_gemm<128><<<gb, 1024, 0, stream>>>(h0, W2, t0, N);
    k_prop<128, true><<<pb128, B, 0, stream>>>(t0, offs, epk, b2, h0, N);
    // --- layer 3 (OUT=64, no relu, into d_out) ---
    k_gemm<64><<<gb, 1024, 0, stream>>>(h0, W3, t0, N);
    k_prop<64, false><<<pb64, B, 0, stream>>>(t0, offs, epk, b3, out, N);
}

// Round 6
// 471.377 us; speedup vs baseline: 1.5985x; 1.2499x over previous
//
#include <hip/hip_runtime.h>
#include <hip/hip_fp16.h>

// ---------------------------------------------------------------------------
// GCN 3-layer forward on MI355X.
// Pipeline: build deg -> dinv -> CSR(by dst, packed {src,w}) once; per layer:
//   T = H @ W   (fp16 MFMA GEMM, f32 accum; W pre-packed to fragment order)
//   H' = relu( segsum_{dst}( T[src] * w_e ) + b )   (gather fp16, acc fp64)
// R2: prop float4 row gathers, packed int2 edge records, fp64 accumulators.
// R3: prop de-shfl'd — one F/4-lane group per node, direct epk loads.
// R4: T stored fp16 — halves random-gather bytes (fabric ceiling ~3.3 TB/s).
// R5: GEMM -> v_mfma_f32_16x16x32_f16. No LDS (W-frags L2-resident), H fp16
//     between layers. A/B use the SAME k-slot map, so any HW intra-operand
//     k-permutation cancels in the reduction; C/D layout is the m89-verified
//     col=lane&15, row=(lane>>4)*4+reg.
// ---------------------------------------------------------------------------

typedef _Float16 half8 __attribute__((ext_vector_type(8)));
typedef float floatx4 __attribute__((ext_vector_type(4)));

struct h4 { __half2 a, b; };  // 4 halves = 8 B

__global__ void k_init_deg(int* __restrict__ deg, int n) {
    int i = blockIdx.x * blockDim.x + threadIdx.x;
    if (i < n) deg[i] = 1;  // self-loop contributes 1
}

__global__ void k_hist(const int* __restrict__ dst, int* __restrict__ deg, int E) {
    int e = blockIdx.x * blockDim.x + threadIdx.x;
    if (e < E) atomicAdd(&deg[dst[e]], 1);
}

// per-block (1024 elems) local exclusive scan; block totals to bsum
__global__ __launch_bounds__(256) void k_scan1(const int* __restrict__ deg,
                                               int* __restrict__ loc,
                                               int* __restrict__ bsum, int n) {
    __shared__ int sh[256];
    int tid = threadIdx.x;
    int base = blockIdx.x * 1024 + tid * 4;
    int v[4];
#pragma unroll
    for (int j = 0; j < 4; j++) v[j] = (base + j < n) ? deg[base + j] : 0;
    int tsum = v[0] + v[1] + v[2] + v[3];
    int val = tsum;
    sh[tid] = val;
    __syncthreads();
    for (int off = 1; off < 256; off <<= 1) {
        int o = (tid >= off) ? sh[tid - off] : 0;
        __syncthreads();
        val += o;
        sh[tid] = val;
        __syncthreads();
    }
    if (tid == 255) bsum[blockIdx.x] = val;
    int run = val - tsum;  // exclusive over thread sums
#pragma unroll
    for (int j = 0; j < 4; j++) {
        if (base + j < n) loc[base + j] = run;
        run += v[j];
    }
}

// single block: exclusive scan of nb block sums (nb <= 256)
__global__ __launch_bounds__(256) void k_scan2(int* __restrict__ bsum, int nb) {
    __shared__ int sh[256];
    int tid = threadIdx.x;
    int orig = (tid < nb) ? bsum[tid] : 0;
    int val = orig;
    sh[tid] = val;
    __syncthreads();
    for (int off = 1; off < 256; off <<= 1) {
        int o = (tid >= off) ? sh[tid - off] : 0;
        __syncthreads();
        val += o;
        sh[tid] = val;
        __syncthreads();
    }
    if (tid < nb) bsum[tid] = val - orig;      // exclusive
    if (tid == nb - 1) bsum[nb] = val;         // total = E + N
}

__global__ void k_scan3(const int* __restrict__ deg, int* __restrict__ offs,
                        const int* __restrict__ bsum, int* __restrict__ cursor,
                        float* __restrict__ dinv, int n, int nb) {
    int i = blockIdx.x * blockDim.x + threadIdx.x;
    if (i < n) {
        int off = offs[i] + bsum[i >> 10];
        offs[i] = off;
        cursor[i] = off;
        dinv[i] = rsqrtf((float)deg[i]);
    }
    if (i == 0) offs[n] = bsum[nb];
}

__global__ void k_fill(const int* __restrict__ esrc, const int* __restrict__ edst,
                       const float* __restrict__ dinv, int* __restrict__ cursor,
                       int2* __restrict__ epk, int E, int n) {
    int e = blockIdx.x * blockDim.x + threadIdx.x;
    if (e < E) {
        int s = esrc[e], d = edst[e];
        int pos = atomicAdd(&cursor[d], 1);
        float w = dinv[s] * dinv[d];
        epk[pos] = int2{s, __float_as_int(w)};
    } else if (e < E + n) {
        int i = e - E;
        int pos = atomicAdd(&cursor[i], 1);
        float di = dinv[i];
        epk[pos] = int2{i, __float_as_int(di * di)};
    }
}

// Pack W[128xF] fp32 -> fp16 fragment order:
//   slot(((ks*NT)+ct)*64 + lane)*8 + j  <-  W[ks*32 + (lane>>4)*8 + j][ct*16 + (lane&15)]
// One thread per (ks,ct,lane) slot; 8 j's each.
template <int F>
__global__ void k_wfrag(const float* __restrict__ W, _Float16* __restrict__ Wf) {
    constexpr int NT = F / 16;
    int tid = blockIdx.x * blockDim.x + threadIdx.x;   // 0 .. 4*NT*64-1
    if (tid >= 4 * NT * 64) return;
    int lane = tid & 63;
    int ct = (tid >> 6) % NT;
    int ks = tid / (64 * NT);
    int k0 = ks * 32 + (lane >> 4) * 8;
    int c  = ct * 16 + (lane & 15);
#pragma unroll
    for (int j = 0; j < 8; j++)
        Wf[(size_t)tid * 8 + j] = (_Float16)W[(k0 + j) * F + c];
}

// T[N,F] = H[N,128] @ W[128,F] via v_mfma_f32_16x16x32_f16.
// 512 threads = 8 waves, 16 rows/wave -> 128 rows/block. No LDS: B-frags
// streamed from L2-resident Wf; A from global (fp16, or fp32-converted for
// layer 1). Output stored fp16.
template <int F, bool IN32>
__global__ __launch_bounds__(512) void k_gemm_mfma(const void* __restrict__ Hv,
                                                   const _Float16* __restrict__ Wf,
                                                   _Float16* __restrict__ T, int n) {
    constexpr int NT = F / 16;                 // col tiles: 8 or 4
    int wave = threadIdx.x >> 6, lane = threadIdx.x & 63;
    int row0 = blockIdx.x * 128 + wave * 16;
    int arow = min(row0 + (lane & 15), n - 1); // clamp; stores guarded
    int k0 = (lane >> 4) * 8;
    const _Float16* Hh = (const _Float16*)Hv;
    const float*    Hf = (const float*)Hv;
    floatx4 acc[NT];
#pragma unroll
    for (int t = 0; t < NT; t++) acc[t] = floatx4{0.f, 0.f, 0.f, 0.f};
#pragma unroll
    for (int ks = 0; ks < 4; ks++) {
        half8 a;
        if constexpr (IN32) {
            const float* p = Hf + (size_t)arow * 128 + ks * 32 + k0;
            float4 f0 = *(const float4*)p;
            float4 f1 = *(const float4*)(p + 4);
            a[0] = (_Float16)f0.x; a[1] = (_Float16)f0.y;
            a[2] = (_Float16)f0.z; a[3] = (_Float16)f0.w;
            a[4] = (_Float16)f1.x; a[5] = (_Float16)f1.y;
            a[6] = (_Float16)f1.z; a[7] = (_Float16)f1.w;
        } else {
            a = *(const half8*)(Hh + (size_t)arow * 128 + ks * 32 + k0);
        }
#pragma unroll
        for (int t = 0; t < NT; t++) {
            half8 b = *(const half8*)(Wf + ((size_t)(ks * NT + t) * 64 + lane) * 8);
            acc[t] = __builtin_amdgcn_mfma_f32_16x16x32_f16(a, b, acc[t], 0, 0, 0);
        }
    }
    // C/D layout (m89-verified): col = lane&15, row = (lane>>4)*4 + reg
    int rbase = row0 + (lane >> 4) * 4;
    int cl = lane & 15;
#pragma unroll
    for (int t = 0; t < NT; t++) {
#pragma unroll
        for (int r = 0; r < 4; r++) {
            int rr = rbase + r;
            if (rr < n) T[(size_t)rr * F + t * 16 + cl] = (_Float16)acc[t][r];
        }
    }
}

// prop: one GRP-lane group per dst node (GRP = F/4). Each lane gathers 4
// halves (8 B) of the fp16 T row; 4 edges unrolled (4 gathers in flight).
// epk loads are group-uniform (L1 broadcast). f64 accumulators. Output
// fp16 (inter-layer) or fp32 (final, d_out).
template <int F, bool RELU, typename OT>
__global__ __launch_bounds__(256) void k_prop(const __half* __restrict__ T,
                                              const int* __restrict__ offs,
                                              const int2* __restrict__ epk,
                                              const float* __restrict__ bias,
                                              OT* __restrict__ Out, int n) {
    constexpr int GRP = F / 4;              // 32 (F=128) or 16 (F=64)
    int g  = (int)((blockIdx.x * blockDim.x + threadIdx.x) / GRP);  // node id
    int fl = threadIdx.x % GRP;             // feature lane
    if (g >= n) return;
    int j = offs[g], end = offs[g + 1];
    double a0 = 0.0, a1 = 0.0, a2 = 0.0, a3 = 0.0;
    for (; j + 4 <= end; j += 4) {
        int2 e0 = epk[j + 0];
        int2 e1 = epk[j + 1];
        int2 e2 = epk[j + 2];
        int2 e3 = epk[j + 3];
        h4 v0 = *(const h4*)&T[(size_t)e0.x * F + fl * 4];
        h4 v1 = *(const h4*)&T[(size_t)e1.x * F + fl * 4];
        h4 v2 = *(const h4*)&T[(size_t)e2.x * F + fl * 4];
        h4 v3 = *(const h4*)&T[(size_t)e3.x * F + fl * 4];
        float w0 = __int_as_float(e0.y), w1 = __int_as_float(e1.y);
        float w2 = __int_as_float(e2.y), w3 = __int_as_float(e3.y);
        float2 f0a = __half22float2(v0.a), f0b = __half22float2(v0.b);
        float2 f1a = __half22float2(v1.a), f1b = __half22float2(v1.b);
        float2 f2a = __half22float2(v2.a), f2b = __half22float2(v2.b);
        float2 f3a = __half22float2(v3.a), f3b = __half22float2(v3.b);
        a0 += (double)(w0 * f0a.x) + (double)(w1 * f1a.x) +
              (double)(w2 * f2a.x) + (double)(w3 * f3a.x);
        a1 += (double)(w0 * f0a.y) + (double)(w1 * f1a.y) +
              (double)(w2 * f2a.y) + (double)(w3 * f3a.y);
        a2 += (double)(w0 * f0b.x) + (double)(w1 * f1b.x) +
              (double)(w2 * f2b.x) + (double)(w3 * f3b.x);
        a3 += (double)(w0 * f0b.y) + (double)(w1 * f1b.y) +
              (double)(w2 * f2b.y) + (double)(w3 * f3b.y);
    }
    for (; j < end; j++) {
        int2 e = epk[j];
        float w = __int_as_float(e.y);
        h4 v = *(const h4*)&T[(size_t)e.x * F + fl * 4];
        float2 fa = __half22float2(v.a), fb = __half22float2(v.b);
        a0 += (double)(w * fa.x);
        a1 += (double)(w * fa.y);
        a2 += (double)(w * fb.x);
        a3 += (double)(w * fb.y);
    }
    float4 b = *(const float4*)&bias[fl * 4];
    float r0 = (float)a0 + b.x;
    float r1 = (float)a1 + b.y;
    float r2 = (float)a2 + b.z;
    float r3 = (float)a3 + b.w;
    if (RELU) {
        r0 = fmaxf(r0, 0.f); r1 = fmaxf(r1, 0.f);
        r2 = fmaxf(r2, 0.f); r3 = fmaxf(r3, 0.f);
    }
    if constexpr (sizeof(OT) == 2) {
        h4 pk;
        pk.a = __floats2half2_rn(r0, r1);
        pk.b = __floats2half2_rn(r2, r3);
        *(h4*)&Out[(size_t)g * F + fl * 4] = pk;
    } else {
        *(float4*)&Out[(size_t)g * F + fl * 4] = float4{r0, r1, r2, r3};
    }
}

extern "C" void kernel_launch(void* const* d_in, const int* in_sizes, int n_in,
                              void* d_out, int out_size, void* d_ws, size_t ws_size,
                              hipStream_t stream) {
    const float* x  = (const float*)d_in[0];
    const int*   ei = (const int*)d_in[1];
    const float* W1 = (const float*)d_in[2];
    const float* b1 = (const float*)d_in[3];
    const float* W2 = (const float*)d_in[4];
    const float* b2 = (const float*)d_in[5];
    const float* W3 = (const float*)d_in[6];
    const float* b3 = (const float*)d_in[7];
    float* out = (float*)d_out;

    const int HID = in_sizes[3];            // 128
    const int IN  = in_sizes[2] / HID;      // 128
    const int N   = in_sizes[0] / IN;       // 100000
    const int E   = in_sizes[1] / 2;        // 1600000
    const int nb  = (N + 1023) / 1024;      // scan blocks

    const int* esrc = ei;
    const int* edst = ei + E;

    // workspace carve-up (256B aligned)
    char* p = (char*)d_ws;
    auto alloc = [&](size_t bytes) {
        void* r = (void*)p;
        p += (bytes + 255) & ~(size_t)255;
        return r;
    };
    int*      deg    = (int*)alloc((size_t)N * 4);
    float*    dinv   = (float*)alloc((size_t)N * 4);
    int*      offs   = (int*)alloc((size_t)(N + 1) * 4);
    int*      bsum   = (int*)alloc((size_t)(nb + 2) * 4);
    int*      cursor = (int*)alloc((size_t)N * 4);
    int2*     epk    = (int2*)alloc((size_t)(E + N) * 8);
    _Float16* t0     = (_Float16*)alloc((size_t)N * 128 * 2);
    _Float16* h0     = (_Float16*)alloc((size_t)N * 128 * 2);
    _Float16* wf1    = (_Float16*)alloc((size_t)128 * 128 * 2);
    _Float16* wf2    = (_Float16*)alloc((size_t)128 * 128 * 2);
    _Float16* wf3    = (_Float16*)alloc((size_t)128 * 64 * 2);
    (void)ws_size; (void)n_in; (void)out_size;

    const int B = 256;
    // --- graph norm + CSR build (once; reused by all 3 layers) ---
    k_init_deg<<<(N + B - 1) / B, B, 0, stream>>>(deg, N);
    k_hist<<<(E + B - 1) / B, B, 0, stream>>>(edst, deg, E);
    k_scan1<<<nb, B, 0, stream>>>(deg, offs, bsum, N);
    k_scan2<<<1, B, 0, stream>>>(bsum, nb);
    k_scan3<<<(N + B - 1) / B, B, 0, stream>>>(deg, offs, bsum, cursor, dinv, N, nb);
    k_fill<<<(E + N + B - 1) / B, B, 0, stream>>>(esrc, edst, dinv, cursor, epk, E, N);
    // --- W -> fp16 fragment packs ---
    k_wfrag<128><<<8, 256, 0, stream>>>(W1, wf1);
    k_wfrag<128><<<8, 256, 0, stream>>>(W2, wf2);
    k_wfrag<64><<<4, 256, 0, stream>>>(W3, wf3);

    const int gb    = (N + 127) / 128;                     // gemm row-blocks
    const int pb128 = (int)(((size_t)N * 32 + B - 1) / B); // prop F=128 blocks
    const int pb64  = (int)(((size_t)N * 16 + B - 1) / B); // prop F=64 blocks
    // --- layer 1 (A from fp32 x, converted in-kernel) ---
    k_gemm_mfma<128, true><<<gb, 512, 0, stream>>>(x, wf1, t0, N);
    k_prop<128, true, __half><<<pb128, B, 0, stream>>>((const __half*)t0, offs, epk, b1, (__half*)h0, N);
    // --- layer 2 ---
    k_gemm_mfma<128, false><<<gb, 512, 0, stream>>>(h0, wf2, t0, N);
    k_prop<128, true, __half><<<pb128, B, 0, stream>>>((const __half*)t0, offs, epk, b2, (__half*)h0, N);
    // --- layer 3 (OUT=64, no relu, fp32 into d_out) ---
    k_gemm_mfma<64, false><<<gb, 512, 0, stream>>>(h0, wf3, t0, N);
    k_prop<64, false, float><<<pb64, B, 0, stream>>>((const __half*)t0, offs, epk, b3, out, N);
}